// Round 2
// baseline (213.850 us; speedup 1.0000x reference)
//
#include <hip/hip_runtime.h>

typedef unsigned short u16;
typedef short bf16x8 __attribute__((ext_vector_type(8)));
typedef float floatx4 __attribute__((ext_vector_type(4)));

#define L_TOT 65536
#define OUT_CTX 16777216           // 2*128*65536 attention elems
#define OUT_CLS (OUT_CTX + 512)

__device__ __forceinline__ u16 f2b(float f) {           // fp32 -> bf16 RNE
  unsigned int u = __float_as_uint(f);
  u += 0x7fffu + ((u >> 16) & 1u);
  return (u16)(u >> 16);
}
__device__ __forceinline__ float blo(unsigned int u) { return __uint_as_float(u << 16); }
__device__ __forceinline__ float bhi(unsigned int u) { return __uint_as_float(u & 0xffff0000u); }

// ---- prepack: W (128x128) -> A-fragment-linear bf16 [mt][ks][lane][8]
// A layout for mfma_f32_16x16x32_bf16: A[m = lane&15][k = (lane>>4)*8 + j]
__device__ __forceinline__ float pack_val(const float* W, int eo) {
  int mt = eo >> 11;
  int rem = eo & 2047;
  int ks = rem >> 9;
  int lane = (rem >> 3) & 63;
  int j = rem & 7;
  int row = mt * 16 + (lane & 15);
  int col = ks * 32 + (lane >> 4) * 8 + j;
  return W[row * 128 + col];
}

__global__ __launch_bounds__(256) void kP(
    const float* __restrict__ Wk, const float* __restrict__ Wq,
    const float* __restrict__ Wv, const float* __restrict__ Wr,
    const float* __restrict__ CLS,
    float* __restrict__ S, float* __restrict__ Cnum,
    u16* __restrict__ wkv, u16* __restrict__ wqf, u16* __restrict__ wrf) {
  const int t = threadIdx.x;
  if (blockIdx.x < 32) {
    #pragma unroll
    for (int i = 0; i < 8; ++i) {
      int e = blockIdx.x * 2048 + i * 256 + t;            // 0..65535
      if (e < 32768) {                                    // [16 mt] = Wk rows then Wv rows
        wkv[e] = f2b(pack_val(e < 16384 ? Wk : Wv, e & 16383));
      } else if (e < 49152) {
        int eq = e - 32768;
        wqf[eq] = f2b(pack_val(Wq, eq));
      } else {
        int er = e - 49152;
        wrf[er] = f2b(pack_val(Wr, er));
      }
    }
  } else {
    // init S / Cnum with the 4 CLS columns' contributions (no shift: |CLS|<~4)
    int n = t >> 7, r = t & 127;
    float s = 0.f;
    #pragma unroll
    for (int j = 0; j < 4; ++j) s += __expf(CLS[(n * 128 + r) * 4 + j]);
    S[n * 128 + r] = s;
    for (int i = 0; i < 16; ++i) {
      int o = t * 16 + i;                                 // [n][h][kc][vc]
      int nn = o >> 11;
      int rem = o & 2047;
      int h = rem >> 8;
      int kc = (rem >> 4) & 15;
      int vc = rem & 15;
      float a = 0.f;
      #pragma unroll
      for (int j = 0; j < 4; ++j)
        a += __expf(CLS[(nn * 128 + h * 16 + kc) * 4 + j]) *
             CLS[(nn * 128 + h * 16 + vc) * 4 + j];
      Cnum[o] = a;
    }
  }
}

// ---- reduce kernel: per 64-col tile, keys+values GEMM, E=exp(keys), partial S and
//      context numerator via head-diagonal MFMA, fp32 atomics into ws.
__global__ __launch_bounds__(256) void kA(
    const float* __restrict__ x, const float* __restrict__ bk,
    const float* __restrict__ bv, float* __restrict__ S,
    float* __restrict__ Cnum, const u16* __restrict__ wkv) {
  __shared__ __align__(16) u16 xT[64][136];   // [col][ch], pitch 272B (16B-mult, bank +4/row)
  __shared__ __align__(16) u16 ev[256][72];   // rows 0..127 = E(bf16), 128..255 = V(bf16)
  const int t = threadIdx.x;
  const int w = t >> 6, lane = t & 63;
  const int quad = lane >> 4, lm = lane & 15;
  const int n = blockIdx.x >> 10;
  const int l0 = (blockIdx.x & 1023) << 6;

  // W fragments for this wave's 4 m-tiles (rows w*64 .. w*64+63 of [keys;values])
  bf16x8 wf[4][4];
  #pragma unroll
  for (int mt = 0; mt < 4; ++mt)
    #pragma unroll
    for (int ks = 0; ks < 4; ++ks)
      wf[mt][ks] = *(const bf16x8*)(wkv + ((((w * 4 + mt) * 4 + ks) * 64 + lane) * 8));

  // stage x tile (coalesced float4 reads, transposed bf16 into LDS)
  #pragma unroll
  for (int i = 0; i < 8; ++i) {
    int idx = i * 256 + t;                 // 0..2047
    int c = idx >> 4;                      // channel 0..127
    int l4 = idx & 15;                     // float4 index along l
    float4 v = *(const float4*)(x + (((size_t)(n * 128 + c)) << 16) + l0 + l4 * 4);
    int col = l4 * 4;
    xT[col + 0][c] = f2b(v.x);
    xT[col + 1][c] = f2b(v.y);
    xT[col + 2][c] = f2b(v.z);
    xT[col + 3][c] = f2b(v.w);
  }
  __syncthreads();

  floatx4 z4 = {0.f, 0.f, 0.f, 0.f};
  floatx4 acc[4][4];
  #pragma unroll
  for (int mt = 0; mt < 4; ++mt)
    #pragma unroll
    for (int nt = 0; nt < 4; ++nt) acc[mt][nt] = z4;

  #pragma unroll
  for (int nt = 0; nt < 4; ++nt)
    #pragma unroll
    for (int ks = 0; ks < 4; ++ks) {
      bf16x8 b = *(const bf16x8*)(&xT[nt * 16 + lm][ks * 32 + quad * 8]);
      #pragma unroll
      for (int mt = 0; mt < 4; ++mt)
        acc[mt][nt] = __builtin_amdgcn_mfma_f32_16x16x32_bf16(wf[mt][ks], b, acc[mt][nt], 0, 0, 0);
    }

  // epilogue: bias, exp (keys rows), write E/V bf16 to LDS.  C-layout: row=quad*4+j, col=lm
  const bool iskey = (w < 2);
  #pragma unroll
  for (int mt = 0; mt < 4; ++mt)
    #pragma unroll
    for (int j = 0; j < 4; ++j) {
      int R = w * 64 + mt * 16 + quad * 4 + j;
      float bias = iskey ? bk[R] : bv[R - 128];
      #pragma unroll
      for (int nt = 0; nt < 4; ++nt) {
        float v = acc[mt][nt][j] + bias;
        if (iskey) v = __expf(v);
        ev[R][nt * 16 + lm] = f2b(v);
      }
    }
  __syncthreads();

  // context numerator: per wave 2 heads, D[kc][vc] += sum_l E[h*16+kc,l] * V[h*16+vc,l]
  #pragma unroll
  for (int hh = 0; hh < 2; ++hh) {
    int h = w * 2 + hh;
    floatx4 cacc = z4;
    #pragma unroll
    for (int ks = 0; ks < 2; ++ks) {
      bf16x8 aE = *(const bf16x8*)(&ev[h * 16 + lm][ks * 32 + quad * 8]);
      bf16x8 bV = *(const bf16x8*)(&ev[128 + h * 16 + lm][ks * 32 + quad * 8]);
      cacc = __builtin_amdgcn_mfma_f32_16x16x32_bf16(aE, bV, cacc, 0, 0, 0);
    }
    #pragma unroll
    for (int j = 0; j < 4; ++j)
      atomicAdd(&Cnum[((n * 8 + h) * 16 + quad * 4 + j) * 16 + lm], cacc[j]);
  }

  // S partials: row sums of E
  if (t < 128) {
    float s = 0.f;
    #pragma unroll
    for (int i = 0; i < 8; ++i) {
      uint4 u = *(const uint4*)(&ev[t][i * 8]);
      s += blo(u.x) + bhi(u.x) + blo(u.y) + bhi(u.y) +
           blo(u.z) + bhi(u.z) + blo(u.w) + bhi(u.w);
    }
    atomicAdd(&S[n * 128 + t], s);
  }
}

// ---- finalize: ctx = Cnum/S, emit context_last + CLS_out, pack ctx as zero-padded A-frags
__global__ __launch_bounds__(256) void kF(
    const float* __restrict__ CLS, const float* __restrict__ S,
    const float* __restrict__ Cnum, u16* __restrict__ ctxf,
    float* __restrict__ out) {
  const int t = threadIdx.x;
  for (int e = t; e < 8192; e += 256) {        // [n][h][lane][j]; A[m=lane&15][k=quad*8+j]
    int n = e >> 12;
    int rem = e & 4095;
    int h = rem >> 9;
    int rem2 = rem & 511;
    int lane = rem2 >> 3;
    int j = rem2 & 7;
    int m = lane & 15;
    int k = (lane >> 4) * 8 + j;               // 0..31; k>=16 zero-padded
    float v = 0.f;
    if (k < 16) v = Cnum[((n * 8 + h) * 16 + k) * 16 + m] / S[n * 128 + h * 16 + k];
    ctxf[e] = f2b(v);
  }
  // context_last = ctx[:, head 7] -> [n][kc][vc]  (512 elems, 256 threads -> LOOP, not guard)
  for (int e = t; e < 512; e += 256) {
    int n = e >> 8;
    int kc = (e >> 4) & 15;
    int vc = e & 15;
    out[OUT_CTX + e] = Cnum[((n * 8 + 7) * 16 + kc) * 16 + vc] / S[n * 128 + 112 + kc];
  }
  if (t < 128) {                               // CLS_out[n][vc][j], head 7, CLS query cols
    int n = t >> 6;
    int vc = (t >> 2) & 15;
    int j = t & 3;
    float den = 0.f, num = 0.f;
    #pragma unroll
    for (int kc = 0; kc < 16; ++kc) {
      float e_ = __expf(CLS[(n * 128 + 112 + kc) * 4 + j]);
      den += e_;
      num += e_ * (Cnum[((n * 8 + 7) * 16 + kc) * 16 + vc] / S[n * 128 + 112 + kc]);
    }
    out[OUT_CLS + t] = num / den;
  }
}

// ---- map kernel: queries GEMM -> channel softmax -> ctx^T*q MFMA -> Wr GEMM -> store
__global__ __launch_bounds__(256) void kB(
    const float* __restrict__ x, const float* __restrict__ bq,
    const float* __restrict__ br, const u16* __restrict__ wqf,
    const u16* __restrict__ wrf, const u16* __restrict__ ctxf,
    float* __restrict__ out) {
  __shared__ __align__(16) u16 xT[64][136];
  __shared__ __align__(16) u16 qT[64][136];    // softmaxed queries, [col][ch] bf16
  __shared__ __align__(16) u16 aT[64][136];    // att, [col][ch] bf16
  const int t = threadIdx.x;
  const int w = t >> 6, lane = t & 63;
  const int quad = lane >> 4, lm = lane & 15;
  const int n = blockIdx.x >> 10;
  const int l0 = (blockIdx.x & 1023) << 6;

  bf16x8 wq[2][4];
  #pragma unroll
  for (int mt = 0; mt < 2; ++mt)
    #pragma unroll
    for (int ks = 0; ks < 4; ++ks)
      wq[mt][ks] = *(const bf16x8*)(wqf + ((((w * 2 + mt) * 4 + ks) * 64 + lane) * 8));

  #pragma unroll
  for (int i = 0; i < 8; ++i) {
    int idx = i * 256 + t;
    int c = idx >> 4;
    int l4 = idx & 15;
    float4 v = *(const float4*)(x + (((size_t)(n * 128 + c)) << 16) + l0 + l4 * 4);
    int col = l4 * 4;
    xT[col + 0][c] = f2b(v.x);
    xT[col + 1][c] = f2b(v.y);
    xT[col + 2][c] = f2b(v.z);
    xT[col + 3][c] = f2b(v.w);
  }
  __syncthreads();

  floatx4 z4 = {0.f, 0.f, 0.f, 0.f};
  floatx4 acc[2][4];
  #pragma unroll
  for (int mt = 0; mt < 2; ++mt)
    #pragma unroll
    for (int nt = 0; nt < 4; ++nt) acc[mt][nt] = z4;

  #pragma unroll
  for (int nt = 0; nt < 4; ++nt)
    #pragma unroll
    for (int ks = 0; ks < 4; ++ks) {
      bf16x8 b = *(const bf16x8*)(&xT[nt * 16 + lm][ks * 32 + quad * 8]);
      #pragma unroll
      for (int mt = 0; mt < 2; ++mt)
        acc[mt][nt] = __builtin_amdgcn_mfma_f32_16x16x32_bf16(wq[mt][ks], b, acc[mt][nt], 0, 0, 0);
    }

  // per-column softmax over the 16 channels of each head (wave-local: 4 regs x 4 quads)
  #pragma unroll
  for (int mt = 0; mt < 2; ++mt) {
    int h = w * 2 + mt;
    float bqv[4];
    #pragma unroll
    for (int j = 0; j < 4; ++j) bqv[j] = bq[h * 16 + quad * 4 + j];
    #pragma unroll
    for (int nt = 0; nt < 4; ++nt) {
      float e[4];
      float ssum = 0.f;
      #pragma unroll
      for (int j = 0; j < 4; ++j) {
        e[j] = __expf(acc[mt][nt][j] + bqv[j]);
        ssum += e[j];
      }
      ssum += __shfl_xor(ssum, 16);
      ssum += __shfl_xor(ssum, 32);
      float inv = 1.f / ssum;
      #pragma unroll
      for (int j = 0; j < 4; ++j)
        qT[nt * 16 + lm][h * 16 + quad * 4 + j] = f2b(e[j] * inv);
    }
  }
  // same wave wrote these qT rows -> no barrier needed before reading them back

  // att[h*16+vc, col] = sum_kc ctx[h,kc,vc] * q[h*16+kc, col]  (A zero-padded for k>=16)
  #pragma unroll
  for (int mt = 0; mt < 2; ++mt) {
    int h = w * 2 + mt;
    bf16x8 aC = *(const bf16x8*)(ctxf + (((size_t)(n * 8 + h)) * 64 + lane) * 8);
    #pragma unroll
    for (int nt = 0; nt < 4; ++nt) {
      bf16x8 bqv_ = *(const bf16x8*)(&qT[nt * 16 + lm][h * 16 + (quad & 1) * 8]);
      floatx4 d = __builtin_amdgcn_mfma_f32_16x16x32_bf16(aC, bqv_, z4, 0, 0, 0);
      #pragma unroll
      for (int j = 0; j < 4; ++j)
        aT[nt * 16 + lm][h * 16 + quad * 4 + j] = f2b(d[j]);
    }
  }
  __syncthreads();   // final GEMM reads all heads' att rows

  bf16x8 wr[2][4];
  #pragma unroll
  for (int mt = 0; mt < 2; ++mt)
    #pragma unroll
    for (int ks = 0; ks < 4; ++ks)
      wr[mt][ks] = *(const bf16x8*)(wrf + ((((w * 2 + mt) * 4 + ks) * 64 + lane) * 8));

  floatx4 acc2[2][4];
  #pragma unroll
  for (int mt = 0; mt < 2; ++mt)
    #pragma unroll
    for (int nt = 0; nt < 4; ++nt) acc2[mt][nt] = z4;

  #pragma unroll
  for (int nt = 0; nt < 4; ++nt)
    #pragma unroll
    for (int ks = 0; ks < 4; ++ks) {
      bf16x8 b = *(const bf16x8*)(&aT[nt * 16 + lm][ks * 32 + quad * 8]);
      #pragma unroll
      for (int mt = 0; mt < 2; ++mt)
        acc2[mt][nt] = __builtin_amdgcn_mfma_f32_16x16x32_bf16(wr[mt][ks], b, acc2[mt][nt], 0, 0, 0);
    }

  #pragma unroll
  for (int mt = 0; mt < 2; ++mt)
    #pragma unroll
    for (int j = 0; j < 4; ++j) {
      int R = (w * 2 + mt) * 16 + quad * 4 + j;
      float bias = br[R];
      #pragma unroll
      for (int nt = 0; nt < 4; ++nt)
        out[(((size_t)(n * 128 + R)) << 16) + l0 + nt * 16 + lm] = acc2[mt][nt][j] + bias;
    }
}

extern "C" void kernel_launch(void* const* d_in, const int* in_sizes, int n_in,
                              void* d_out, int out_size, void* d_ws, size_t ws_size,
                              hipStream_t stream) {
  const float* x   = (const float*)d_in[0];
  const float* CLS = (const float*)d_in[1];
  const float* Wk  = (const float*)d_in[2];
  const float* bk  = (const float*)d_in[3];
  const float* Wq  = (const float*)d_in[4];
  const float* bq  = (const float*)d_in[5];
  const float* Wv  = (const float*)d_in[6];
  const float* bv  = (const float*)d_in[7];
  const float* Wr  = (const float*)d_in[8];
  const float* br  = (const float*)d_in[9];
  float* out = (float*)d_out;
  char* ws = (char*)d_ws;
  float* S    = (float*)(ws + 0);        // 2*128 f32
  float* Cnum = (float*)(ws + 1024);     // 2*8*16*16 f32
  u16* ctxf   = (u16*)(ws + 17408);      // 2*8*64*8 bf16 A-frags
  u16* wkv    = (u16*)(ws + 33792);      // 16*4*64*8 bf16
  u16* wqf    = (u16*)(ws + 99328);      // 8*4*64*8 bf16
  u16* wrf    = (u16*)(ws + 132096);     // 8*4*64*8 bf16

  kP<<<33, 256, 0, stream>>>(Wk, Wq, Wv, Wr, CLS, S, Cnum, wkv, wqf, wrf);
  kA<<<2048, 256, 0, stream>>>(x, bk, bv, S, Cnum, wkv);
  kF<<<1, 256, 0, stream>>>(CLS, S, Cnum, ctxf, out);
  kB<<<2048, 256, 0, stream>>>(x, bq, br, wqf, wrf, ctxf, out);
}

// Round 3
// 176.374 us; speedup vs baseline: 1.2125x; 1.2125x over previous
//
#include <hip/hip_runtime.h>

typedef unsigned short u16;
typedef short bf16x8 __attribute__((ext_vector_type(8)));
typedef float floatx4 __attribute__((ext_vector_type(4)));

#define L_TOT 65536
#define OUT_CTX 16777216           // 2*128*65536 attention elems
#define OUT_CLS (OUT_CTX + 512)

__device__ __forceinline__ u16 f2b(float f) {           // fp32 -> bf16 RNE
  unsigned int u = __float_as_uint(f);
  u += 0x7fffu + ((u >> 16) & 1u);
  return (u16)(u >> 16);
}
__device__ __forceinline__ float blo(unsigned int u) { return __uint_as_float(u << 16); }
__device__ __forceinline__ float bhi(unsigned int u) { return __uint_as_float(u & 0xffff0000u); }

// ---- prepack: W (128x128) -> A-fragment-linear bf16 [rb][ks][lane][8]
// A layout for mfma_f32_16x16x32_bf16: A[m = lane&15][k = (lane>>4)*8 + j]
__device__ __forceinline__ float pack_val(const float* W, int eo) {
  int mt = eo >> 11;
  int rem = eo & 2047;
  int ks = rem >> 9;
  int lane = (rem >> 3) & 63;
  int j = rem & 7;
  int row = mt * 16 + (lane & 15);
  int col = ks * 32 + (lane >> 4) * 8 + j;
  return W[row * 128 + col];
}

__global__ __launch_bounds__(256) void kP(
    const float* __restrict__ Wk, const float* __restrict__ Wq,
    const float* __restrict__ Wv, const float* __restrict__ Wr,
    const float* __restrict__ CLS,
    float* __restrict__ S, float* __restrict__ Cnum,
    u16* __restrict__ wkv, u16* __restrict__ wqf, u16* __restrict__ wrf) {
  const int t = threadIdx.x;
  if (blockIdx.x < 32) {
    #pragma unroll
    for (int i = 0; i < 8; ++i) {
      int e = blockIdx.x * 2048 + i * 256 + t;            // 0..65535
      if (e < 32768) {                                    // rb 0..7 = Wk, 8..15 = Wv
        wkv[e] = f2b(pack_val(e < 16384 ? Wk : Wv, e & 16383));
      } else if (e < 49152) {
        int eq = e - 32768;
        wqf[eq] = f2b(pack_val(Wq, eq));
      } else {
        int er = e - 49152;
        wrf[er] = f2b(pack_val(Wr, er));
      }
    }
  } else {
    // init S / Cnum with the 4 CLS columns' contributions (no shift: |CLS|<~4)
    int n = t >> 7, r = t & 127;
    float s = 0.f;
    #pragma unroll
    for (int j = 0; j < 4; ++j) s += __expf(CLS[(n * 128 + r) * 4 + j]);
    S[n * 128 + r] = s;
    for (int i = 0; i < 16; ++i) {
      int o = t * 16 + i;                                 // [n][h][kc][vc]
      int nn = o >> 11;
      int rem = o & 2047;
      int h = rem >> 8;
      int kc = (rem >> 4) & 15;
      int vc = rem & 15;
      float a = 0.f;
      #pragma unroll
      for (int j = 0; j < 4; ++j)
        a += __expf(CLS[(nn * 128 + h * 16 + kc) * 4 + j]) *
             CLS[(nn * 128 + h * 16 + vc) * 4 + j];
      Cnum[o] = a;
    }
  }
}

// ---- reduce kernel v2: 512 blocks x 4 tiles of 64 cols. W frags + bias loaded once,
//      context/S accumulated in registers across tiles, one atomic set per block,
//      register prefetch of next x-tile overlaps the ctx/S phase.
__global__ __launch_bounds__(256) void kA(
    const float* __restrict__ x, const float* __restrict__ bk,
    const float* __restrict__ bv, float* __restrict__ S,
    float* __restrict__ Cnum, const u16* __restrict__ wkv) {
  __shared__ __align__(16) u16 xT[64][136];   // [col][ch]
  __shared__ __align__(16) u16 ev[256][72];   // rows 0..127 = E(bf16), 128..255 = V(bf16)
  const int t = threadIdx.x;
  const int w = t >> 6, lane = t & 63;
  const int quad = lane >> 4, lm = lane & 15;
  const int n = blockIdx.x >> 8;              // 512 blocks
  const int l0base = (blockIdx.x & 255) << 8; // 256 cols per block

  const int sc = t >> 4;                      // staging: channel sub-index 0..15
  const int sl4 = t & 15;                     // float4 index along l

  // prefetch tile 0 (issue before the L2-bound wf loads: HBM latency is longer)
  float4 pf[8];
  #pragma unroll
  for (int i = 0; i < 8; ++i) {
    int c = i * 16 + sc;
    pf[i] = *(const float4*)(x + (((size_t)(n * 128 + c)) << 16) + l0base + sl4 * 4);
  }

  // W fragments: wave w owns key row-blocks {2w,2w+1} and value row-blocks {8+2w,8+2w+1}
  bf16x8 wf[4][4];
  #pragma unroll
  for (int mt = 0; mt < 4; ++mt) {
    int rb = (mt < 2) ? (2 * w + mt) : (8 + 2 * w + (mt - 2));
    #pragma unroll
    for (int ks = 0; ks < 4; ++ks)
      wf[mt][ks] = *(const bf16x8*)(wkv + (((rb * 4 + ks) * 64 + lane) * 8));
  }
  // bias per (mt, j), loaded once
  float bias_[4][4];
  #pragma unroll
  for (int mt = 0; mt < 4; ++mt)
    #pragma unroll
    for (int j = 0; j < 4; ++j) {
      int r = w * 32 + (mt & 1) * 16 + quad * 4 + j;
      bias_[mt][j] = (mt < 2) ? bk[r] : bv[r];
    }

  floatx4 z4 = {0.f, 0.f, 0.f, 0.f};
  floatx4 cacc[2] = {z4, z4};                 // context accumulators (2 heads per wave)
  float sacc = 0.f;                           // S accumulator (threads 0..127)

  for (int tile = 0; tile < 4; ++tile) {
    // store prefetched x-tile (transposed bf16)
    {
      int c = sc;  // base channel for i=0
      #pragma unroll
      for (int i = 0; i < 8; ++i) {
        int cc = i * 16 + sc;
        int col = sl4 * 4;
        xT[col + 0][cc] = f2b(pf[i].x);
        xT[col + 1][cc] = f2b(pf[i].y);
        xT[col + 2][cc] = f2b(pf[i].z);
        xT[col + 3][cc] = f2b(pf[i].w);
      }
      (void)c;
    }
    __syncthreads();                          // barrier A

    floatx4 acc[4][4];
    #pragma unroll
    for (int mt = 0; mt < 4; ++mt)
      #pragma unroll
      for (int nt = 0; nt < 4; ++nt) acc[mt][nt] = z4;

    #pragma unroll
    for (int nt = 0; nt < 4; ++nt)
      #pragma unroll
      for (int ks = 0; ks < 4; ++ks) {
        bf16x8 b = *(const bf16x8*)(&xT[nt * 16 + lm][ks * 32 + quad * 8]);
        #pragma unroll
        for (int mt = 0; mt < 4; ++mt)
          acc[mt][nt] = __builtin_amdgcn_mfma_f32_16x16x32_bf16(wf[mt][ks], b, acc[mt][nt], 0, 0, 0);
      }

    // epilogue: bias, exp on key rows; write E/V bf16 to LDS. C-layout: row=quad*4+j, col=lm
    #pragma unroll
    for (int mt = 0; mt < 4; ++mt)
      #pragma unroll
      for (int j = 0; j < 4; ++j) {
        int R = ((mt < 2) ? 0 : 128) + w * 32 + (mt & 1) * 16 + quad * 4 + j;
        #pragma unroll
        for (int nt = 0; nt < 4; ++nt) {
          float v = acc[mt][nt][j] + bias_[mt][j];
          if (mt < 2) v = __expf(v);
          ev[R][nt * 16 + lm] = f2b(v);
        }
      }

    // prefetch next tile (overlaps barrier + ctx/S phase)
    if (tile < 3) {
      int l0 = l0base + (tile + 1) * 64;
      #pragma unroll
      for (int i = 0; i < 8; ++i) {
        int c = i * 16 + sc;
        pf[i] = *(const float4*)(x + (((size_t)(n * 128 + c)) << 16) + l0 + sl4 * 4);
      }
    }
    __syncthreads();                          // barrier B

    // context: D[kc][vc] += sum_l E[h*16+kc,l] * V[h*16+vc,l]  (accumulate in regs)
    #pragma unroll
    for (int hh = 0; hh < 2; ++hh) {
      int h = w * 2 + hh;
      #pragma unroll
      for (int ks = 0; ks < 2; ++ks) {
        bf16x8 aE = *(const bf16x8*)(&ev[h * 16 + lm][ks * 32 + quad * 8]);
        bf16x8 bV = *(const bf16x8*)(&ev[128 + h * 16 + lm][ks * 32 + quad * 8]);
        cacc[hh] = __builtin_amdgcn_mfma_f32_16x16x32_bf16(aE, bV, cacc[hh], 0, 0, 0);
      }
    }
    // S partials: row sums of E (accumulate in regs)
    if (t < 128) {
      #pragma unroll
      for (int i = 0; i < 8; ++i) {
        uint4 u = *(const uint4*)(&ev[t][i * 8]);
        sacc += blo(u.x) + bhi(u.x) + blo(u.y) + bhi(u.y) +
                blo(u.z) + bhi(u.z) + blo(u.w) + bhi(u.w);
      }
    }
    // next iteration's barrier A protects ev rewrites against these reads
  }

  // one atomic set per block
  #pragma unroll
  for (int hh = 0; hh < 2; ++hh) {
    int h = w * 2 + hh;
    #pragma unroll
    for (int j = 0; j < 4; ++j)
      atomicAdd(&Cnum[((n * 8 + h) * 16 + quad * 4 + j) * 16 + lm], cacc[hh][j]);
  }
  if (t < 128) atomicAdd(&S[n * 128 + t], sacc);
}

// ---- finalize: ctx = Cnum/S, emit context_last + CLS_out, pack ctx as zero-padded A-frags
__global__ __launch_bounds__(256) void kF(
    const float* __restrict__ CLS, const float* __restrict__ S,
    const float* __restrict__ Cnum, u16* __restrict__ ctxf,
    float* __restrict__ out) {
  const int t = threadIdx.x;
  for (int e = t; e < 8192; e += 256) {        // [n][h][lane][j]; A[m=lane&15][k=quad*8+j]
    int n = e >> 12;
    int rem = e & 4095;
    int h = rem >> 9;
    int rem2 = rem & 511;
    int lane = rem2 >> 3;
    int j = rem2 & 7;
    int m = lane & 15;
    int k = (lane >> 4) * 8 + j;               // 0..31; k>=16 zero-padded
    float v = 0.f;
    if (k < 16) v = Cnum[((n * 8 + h) * 16 + k) * 16 + m] / S[n * 128 + h * 16 + k];
    ctxf[e] = f2b(v);
  }
  // context_last = ctx[:, head 7] -> [n][kc][vc]  (512 elems: LOOP, not guard)
  for (int e = t; e < 512; e += 256) {
    int n = e >> 8;
    int kc = (e >> 4) & 15;
    int vc = e & 15;
    out[OUT_CTX + e] = Cnum[((n * 8 + 7) * 16 + kc) * 16 + vc] / S[n * 128 + 112 + kc];
  }
  if (t < 128) {                               // CLS_out[n][vc][j], head 7, CLS query cols
    int n = t >> 6;
    int vc = (t >> 2) & 15;
    int j = t & 3;
    float den = 0.f, num = 0.f;
    #pragma unroll
    for (int kc = 0; kc < 16; ++kc) {
      float e_ = __expf(CLS[(n * 128 + 112 + kc) * 4 + j]);
      den += e_;
      num += e_ * (Cnum[((n * 8 + 7) * 16 + kc) * 16 + vc] / S[n * 128 + 112 + kc]);
    }
    out[OUT_CLS + t] = num / den;
  }
}

// ---- map kernel v2: 512 blocks x 4 tiles. Frags/bias loaded once; prefetch overlap.
__global__ __launch_bounds__(256) void kB(
    const float* __restrict__ x, const float* __restrict__ bq,
    const float* __restrict__ br, const u16* __restrict__ wqf,
    const u16* __restrict__ wrf, const u16* __restrict__ ctxf,
    float* __restrict__ out) {
  __shared__ __align__(16) u16 xT[64][136];
  __shared__ __align__(16) u16 qT[64][136];    // softmaxed queries, [col][ch] bf16
  __shared__ __align__(16) u16 aT[64][136];    // att, [col][ch] bf16
  const int t = threadIdx.x;
  const int w = t >> 6, lane = t & 63;
  const int quad = lane >> 4, lm = lane & 15;
  const int n = blockIdx.x >> 8;
  const int l0base = (blockIdx.x & 255) << 8;

  const int sc = t >> 4;
  const int sl4 = t & 15;

  float4 pf[8];
  #pragma unroll
  for (int i = 0; i < 8; ++i) {
    int c = i * 16 + sc;
    pf[i] = *(const float4*)(x + (((size_t)(n * 128 + c)) << 16) + l0base + sl4 * 4);
  }

  bf16x8 wq[2][4], wr[2][4];
  #pragma unroll
  for (int mt = 0; mt < 2; ++mt)
    #pragma unroll
    for (int ks = 0; ks < 4; ++ks) {
      wq[mt][ks] = *(const bf16x8*)(wqf + ((((w * 2 + mt) * 4 + ks) * 64 + lane) * 8));
      wr[mt][ks] = *(const bf16x8*)(wrf + ((((w * 2 + mt) * 4 + ks) * 64 + lane) * 8));
    }
  bf16x8 aC[2];
  #pragma unroll
  for (int mt = 0; mt < 2; ++mt)
    aC[mt] = *(const bf16x8*)(ctxf + (((size_t)(n * 8 + w * 2 + mt)) * 64 + lane) * 8);

  float bqv_[2][4], brv[2][4];
  #pragma unroll
  for (int mt = 0; mt < 2; ++mt)
    #pragma unroll
    for (int j = 0; j < 4; ++j) {
      bqv_[mt][j] = bq[(w * 2 + mt) * 16 + quad * 4 + j];
      brv[mt][j] = br[(w * 2 + mt) * 16 + quad * 4 + j];
    }

  floatx4 z4 = {0.f, 0.f, 0.f, 0.f};

  for (int tile = 0; tile < 4; ++tile) {
    int l0 = l0base + tile * 64;
    #pragma unroll
    for (int i = 0; i < 8; ++i) {
      int cc = i * 16 + sc;
      int col = sl4 * 4;
      xT[col + 0][cc] = f2b(pf[i].x);
      xT[col + 1][cc] = f2b(pf[i].y);
      xT[col + 2][cc] = f2b(pf[i].z);
      xT[col + 3][cc] = f2b(pf[i].w);
    }
    __syncthreads();                          // barrier A

    floatx4 acc[2][4];
    #pragma unroll
    for (int mt = 0; mt < 2; ++mt)
      #pragma unroll
      for (int nt = 0; nt < 4; ++nt) acc[mt][nt] = z4;

    #pragma unroll
    for (int nt = 0; nt < 4; ++nt)
      #pragma unroll
      for (int ks = 0; ks < 4; ++ks) {
        bf16x8 b = *(const bf16x8*)(&xT[nt * 16 + lm][ks * 32 + quad * 8]);
        #pragma unroll
        for (int mt = 0; mt < 2; ++mt)
          acc[mt][nt] = __builtin_amdgcn_mfma_f32_16x16x32_bf16(wq[mt][ks], b, acc[mt][nt], 0, 0, 0);
      }

    // per-column softmax over the 16 channels of each head (wave-local)
    #pragma unroll
    for (int mt = 0; mt < 2; ++mt) {
      int h = w * 2 + mt;
      #pragma unroll
      for (int nt = 0; nt < 4; ++nt) {
        float e[4];
        float ssum = 0.f;
        #pragma unroll
        for (int j = 0; j < 4; ++j) {
          e[j] = __expf(acc[mt][nt][j] + bqv_[mt][j]);
          ssum += e[j];
        }
        ssum += __shfl_xor(ssum, 16);
        ssum += __shfl_xor(ssum, 32);
        float inv = 1.f / ssum;
        #pragma unroll
        for (int j = 0; j < 4; ++j)
          qT[nt * 16 + lm][h * 16 + quad * 4 + j] = f2b(e[j] * inv);
      }
    }
    // same wave wrote these qT rows -> no barrier before reading them back

    // att[h*16+vc, col] = sum_kc ctx[h,kc,vc] * q[h*16+kc, col]  (A zero-padded k>=16)
    #pragma unroll
    for (int mt = 0; mt < 2; ++mt) {
      int h = w * 2 + mt;
      #pragma unroll
      for (int nt = 0; nt < 4; ++nt) {
        bf16x8 bq_ = *(const bf16x8*)(&qT[nt * 16 + lm][h * 16 + (quad & 1) * 8]);
        floatx4 d = __builtin_amdgcn_mfma_f32_16x16x32_bf16(aC[mt], bq_, z4, 0, 0, 0);
        #pragma unroll
        for (int j = 0; j < 4; ++j)
          aT[nt * 16 + lm][h * 16 + quad * 4 + j] = f2b(d[j]);
      }
    }

    // prefetch next tile (overlaps barrier + final GEMM)
    if (tile < 3) {
      int l0n = l0base + (tile + 1) * 64;
      #pragma unroll
      for (int i = 0; i < 8; ++i) {
        int c = i * 16 + sc;
        pf[i] = *(const float4*)(x + (((size_t)(n * 128 + c)) << 16) + l0n + sl4 * 4);
      }
    }
    __syncthreads();                          // barrier B (all heads' att rows ready)

    floatx4 acc2[2][4];
    #pragma unroll
    for (int mt = 0; mt < 2; ++mt)
      #pragma unroll
      for (int nt = 0; nt < 4; ++nt) acc2[mt][nt] = z4;

    #pragma unroll
    for (int nt = 0; nt < 4; ++nt)
      #pragma unroll
      for (int ks = 0; ks < 4; ++ks) {
        bf16x8 b = *(const bf16x8*)(&aT[nt * 16 + lm][ks * 32 + quad * 8]);
        #pragma unroll
        for (int mt = 0; mt < 2; ++mt)
          acc2[mt][nt] = __builtin_amdgcn_mfma_f32_16x16x32_bf16(wr[mt][ks], b, acc2[mt][nt], 0, 0, 0);
      }

    #pragma unroll
    for (int mt = 0; mt < 2; ++mt)
      #pragma unroll
      for (int j = 0; j < 4; ++j) {
        int R = (w * 2 + mt) * 16 + quad * 4 + j;
        #pragma unroll
        for (int nt = 0; nt < 4; ++nt)
          out[(((size_t)(n * 128 + R)) << 16) + l0 + nt * 16 + lm] = acc2[mt][nt][j] + brv[mt][j];
      }
    // next iteration's barrier A protects xT/aT rewrites against this tile's reads
  }
}

extern "C" void kernel_launch(void* const* d_in, const int* in_sizes, int n_in,
                              void* d_out, int out_size, void* d_ws, size_t ws_size,
                              hipStream_t stream) {
  const float* x   = (const float*)d_in[0];
  const float* CLS = (const float*)d_in[1];
  const float* Wk  = (const float*)d_in[2];
  const float* bk  = (const float*)d_in[3];
  const float* Wq  = (const float*)d_in[4];
  const float* bq  = (const float*)d_in[5];
  const float* Wv  = (const float*)d_in[6];
  const float* bv  = (const float*)d_in[7];
  const float* Wr  = (const float*)d_in[8];
  const float* br  = (const float*)d_in[9];
  float* out = (float*)d_out;
  char* ws = (char*)d_ws;
  float* S    = (float*)(ws + 0);        // 2*128 f32
  float* Cnum = (float*)(ws + 1024);     // 2*8*16*16 f32
  u16* ctxf   = (u16*)(ws + 17408);      // 2*8*64*8 bf16 A-frags
  u16* wkv    = (u16*)(ws + 33792);      // 16*4*64*8 bf16
  u16* wqf    = (u16*)(ws + 99328);      // 8*4*64*8 bf16
  u16* wrf    = (u16*)(ws + 132096);     // 8*4*64*8 bf16

  kP<<<33, 256, 0, stream>>>(Wk, Wq, Wv, Wr, CLS, S, Cnum, wkv, wqf, wrf);
  kA<<<512, 256, 0, stream>>>(x, bk, bv, S, Cnum, wkv);
  kF<<<1, 256, 0, stream>>>(CLS, S, Cnum, ctxf, out);
  kB<<<512, 256, 0, stream>>>(x, bq, br, wqf, wrf, ctxf, out);
}